// Round 1
// baseline (215.110 us; speedup 1.0000x reference)
//
#include <hip/hip_runtime.h>

#define BB 2048
#define TT 2048
#define CC 8
#define AA 27
#define HH 8

// Fused kernel: per-block MLP (recomputed redundantly, trivially cheap) + streaming contraction.
// Each block covers 1024 consecutive idx = half of one sample's T-row, so exactly ONE sample b
// per block -> the per-sample conv kernel/bias can live in LDS, computed by wave 0, lanes 0..7.
// 4 elements per thread, interleaved tid + k*256 so every load/store instruction is a dense
// 2 KB (loads) / 256 B (stores) wave transaction.
__global__ __launch_bounds__(256) void fused_kernel(
    const float* __restrict__ x,          // [B,T,C]
    const float* __restrict__ attrs,      // [B,A]
    const float* __restrict__ w1,         // [A,H]
    const float* __restrict__ b1,         // [H]
    const float* __restrict__ w2,         // [H,C]
    const float* __restrict__ b2,         // [C]
    const float* __restrict__ bw1,        // [A,H]
    const float* __restrict__ bb1,        // [H]
    const float* __restrict__ bw2,        // [H,1]
    const float* __restrict__ bb2,        // [1]
    const float* __restrict__ mask_attrs, // [B,A]
    const float* __restrict__ mask_hidden,// [B,H]
    float* __restrict__ out)              // [B,T]
{
    const int tid = threadIdx.x;
    const int blk = blockIdx.x;           // 0..4095
    const int b   = blk >> 1;             // 2 blocks per sample

    __shared__ float s_hw[HH];
    __shared__ float s_hb[HH];
    __shared__ float s_ker[CC];
    __shared__ float s_bias;

    // ---- per-sample MLP on lanes 0..7 of wave 0 (intra-wave: no barrier needed
    //      between the LDS write of s_hw/s_hb and their read below) ----
    if (tid < 8) {
        const int h = tid;
        float hw = b1[h];
        float hb = bb1[h];
        const float* ab = attrs      + b * AA;
        const float* mb = mask_attrs + b * AA;
        #pragma unroll
        for (int i = 0; i < AA; ++i) {
            const float a = ab[i] * mb[i];
            hw = fmaf(a, w1 [i * HH + h], hw);
            hb = fmaf(a, bw1[i * HH + h], hb);
        }
        const float mh_ = mask_hidden[b * HH + h];
        s_hw[h] = fmaxf(hw, 0.0f) * mh_;
        s_hb[h] = fmaxf(hb, 0.0f) * mh_;

        // layer 2 (needs all 8 hidden values; same wave -> lockstep + lgkmcnt handles it)
        float acc = b2[h];
        #pragma unroll
        for (int j = 0; j < HH; ++j)
            acc = fmaf(s_hw[j], w2[j * CC + h], acc);
        s_ker[h] = tanhf(acc);
        if (h == 0) {
            float accb = bb2[0];
            #pragma unroll
            for (int j = 0; j < HH; ++j)
                accb = fmaf(s_hb[j], bw2[j], accb);
            s_bias = tanhf(accb);
        }
    }
    __syncthreads();

    // ---- broadcast LDS -> registers (same address across wave: conflict-free) ----
    float k[CC];
    #pragma unroll
    for (int c = 0; c < CC; ++c) k[c] = s_ker[c];
    const float bias = s_bias;

    // ---- streaming contraction: 4 elements/thread ----
    const size_t base = (size_t)blk * 1024;
    #pragma unroll
    for (int kk = 0; kk < 4; ++kk) {
        const size_t idx = base + (size_t)kk * 256 + tid;  // all within sample b
        const float4* xp = reinterpret_cast<const float4*>(x + idx * CC);
        const float4 x0 = xp[0];
        const float4 x1 = xp[1];
        float y = bias;
        y = fmaf(x0.x, k[0], y);
        y = fmaf(x0.y, k[1], y);
        y = fmaf(x0.z, k[2], y);
        y = fmaf(x0.w, k[3], y);
        y = fmaf(x1.x, k[4], y);
        y = fmaf(x1.y, k[5], y);
        y = fmaf(x1.z, k[6], y);
        y = fmaf(x1.w, k[7], y);
        out[idx] = (y > 0.0f) ? y : expm1f(y);   // ELU, alpha=1
    }
}

extern "C" void kernel_launch(void* const* d_in, const int* in_sizes, int n_in,
                              void* d_out, int out_size, void* d_ws, size_t ws_size,
                              hipStream_t stream) {
    const float* x    = (const float*)d_in[0];
    const float* at   = (const float*)d_in[1];
    const float* w1   = (const float*)d_in[2];
    const float* b1   = (const float*)d_in[3];
    const float* w2   = (const float*)d_in[4];
    const float* b2   = (const float*)d_in[5];
    const float* bw1  = (const float*)d_in[6];
    const float* bb1  = (const float*)d_in[7];
    const float* bw2  = (const float*)d_in[8];
    const float* bb2  = (const float*)d_in[9];
    const float* ma   = (const float*)d_in[10];
    const float* mh   = (const float*)d_in[11];
    float* out = (float*)d_out;

    const int total = BB * TT;                    // 4,194,304 elements
    fused_kernel<<<total / 1024, 256, 0, stream>>>(
        x, at, w1, b1, w2, b2, bw1, bb1, bw2, bb2, ma, mh, out);
}